// Round 1
// 1509.744 us; speedup vs baseline: 1.0090x; 1.0090x over previous
//
#include <hip/hip_runtime.h>

typedef unsigned short u16;
typedef __attribute__((ext_vector_type(8))) short s8v;    // 8 bf16 = 4 VGPRs (MFMA A/B frag)
typedef __attribute__((ext_vector_type(4))) float f4v;    // MFMA C/D frag
typedef __attribute__((ext_vector_type(4))) unsigned int u32x4;

typedef const __attribute__((address_space(1))) unsigned gas_u32;
typedef __attribute__((address_space(3))) unsigned las_u32;

__device__ __forceinline__ float bf2f(u16 u) { return __uint_as_float(((unsigned)u) << 16); }
__device__ __forceinline__ u16 f2bf(float x) {
  unsigned b = __float_as_uint(x);
  return (u16)((b + 0x7FFFu + ((b >> 16) & 1u)) >> 16);
}

// ---------------------------------------------------------------- weight fp32 -> bf16 (K-padded)
__global__ void convert_w_kernel(const float* __restrict__ src, u16* __restrict__ dst,
                                 int N, int Kreal, int KP) {
  int idx = blockIdx.x * 256 + threadIdx.x;
  if (idx >= N * KP) return;
  int n = idx / KP, k = idx % KP;
  dst[idx] = (k < Kreal) ? f2bf(src[(size_t)n * Kreal + k]) : (u16)0;
}

// ---------------------------------------------------------------- ent_emb fp32 -> bf16, 400 -> ld 416
// one thread = 8 elems. 200000 rows x 52 chunks; chunks 50,51 are zero pad.
__global__ __launch_bounds__(256) void convert_ent_kernel(const float* __restrict__ src,
                                                          u16* __restrict__ dst) {
  int idx = blockIdx.x * 256 + threadIdx.x;
  if (idx >= 200000 * 52) return;
  int c = idx % 52, n = idx / 52;
  u32x4 pk = {0u, 0u, 0u, 0u};
  if (c < 50) {
    const float* p = src + (size_t)n * 400 + c * 8;
    float4 v0 = *(const float4*)(p);
    float4 v1 = *(const float4*)(p + 4);
    pk.x = (unsigned)f2bf(v0.x) | ((unsigned)f2bf(v0.y) << 16);
    pk.y = (unsigned)f2bf(v0.z) | ((unsigned)f2bf(v0.w) << 16);
    pk.z = (unsigned)f2bf(v1.x) | ((unsigned)f2bf(v1.y) << 16);
    pk.w = (unsigned)f2bf(v1.z) | ((unsigned)f2bf(v1.w) << 16);
  }
  *(u32x4*)(dst + (size_t)n * 416 + c * 8) = pk;
}

// ---------------------------------------------------------------- build x0 (bf16, ld 416, pad pre-zeroed)
__global__ void build_x0_kernel(const float* __restrict__ ent_emb, const float* __restrict__ rel_emb,
                                const float* __restrict__ pos_emb, const int* __restrict__ rel_idx,
                                const int* __restrict__ ent_idx, u16* __restrict__ x0) {
  int idx = blockIdx.x * 256 + threadIdx.x;
  if (idx >= 512 * 4 * 400) return;
  int d = idx % 400;
  int l = (idx / 400) % 4;
  int b = idx / 1600;
  float v;
  if (l == 0) v = rel_emb[(size_t)rel_idx[b] * 400 + d];
  else        v = ent_emb[(size_t)ent_idx[b * 3 + l - 1] * 400 + d];
  x0[(size_t)(b * 4 + l) * 416 + d] = f2bf(v + pos_emb[l * 400 + d]);
}

// ---------------------------------------------------------------- MFMA GEMM, 128x128 tile, Ktile 32
// C[m,n] = sum_k A[m,k] * B[n,k] + bias[n].  A bf16 (lda elems, K padded to KP, pad cols zero).
// B: BF32 ? fp32 (ldb = Kreal row stride, zero-fill k>=Kreal) : bf16 (ldb = KP, pre-padded).
// M % 128 == 0; N arbitrary (row-clamped staging + guarded stores).
// SWZ: bijective XCD remap (m204) so the gridDim.x M-blocks sharing one B panel land on one XCD.
template<bool BF32, bool RELU, bool OUTBF, bool SWZ>
__global__ __launch_bounds__(256) void mfma_gemm(
    const u16* __restrict__ A, int lda,
    const void* __restrict__ Bp, int ldb,
    const float* __restrict__ bias,
    void* __restrict__ Cp, long long ldc,
    int N, int KP, int Kreal) {
  __shared__ u16 As[128 * 32];
  __shared__ u16 Bs[128 * 32];
  int m0, n0;
  if (SWZ) {
    int f = blockIdx.y * gridDim.x + blockIdx.x;   // HW dispatch order (x fastest)
    int nwg = gridDim.x * gridDim.y;
    int xcd = f & 7, j = f >> 3;
    int q = nwg >> 3, r = nwg & 7;
    int wg = (xcd < r ? xcd * (q + 1) : r * (q + 1) + (xcd - r) * q) + j;
    int gx = gridDim.x;
    m0 = (wg % gx) * 128;
    n0 = (wg / gx) * 128;
  } else {
    m0 = blockIdx.x * 128;
    n0 = blockIdx.y * 128;
  }
  const int tid = threadIdx.x;
  const int lane = tid & 63, w = tid >> 6;
  const int mw = (w & 1) * 64, nw = (w >> 1) * 64;
  f4v acc[4][4] = {};

  // staging map: flat16 = t*256 + tid -> row = t*64 + (tid>>2), 8 elems at (tid&3)*8
  const int arow = tid >> 2, akq = tid & 3;
  const u16* ag0 = A + (size_t)(m0 + arow) * lda + akq * 8;
  const u16* ag1 = A + (size_t)(m0 + 64 + arow) * lda + akq * 8;
  int br0 = n0 + arow;      if (br0 >= N) br0 = N - 1;
  int br1 = n0 + 64 + arow; if (br1 >= N) br1 = N - 1;
  const u16* bg0 = nullptr; const u16* bg1 = nullptr;
  if (!BF32) {
    bg0 = (const u16*)Bp + (size_t)br0 * ldb + akq * 8;
    bg1 = (const u16*)Bp + (size_t)br1 * ldb + akq * 8;
  }
  const float* Bf = (const float*)Bp;

  u16* lA0 = As + w * 512;          // + lane*8 implicit (HW: uniform base + lane*16B)
  u16* lA1 = As + 2048 + w * 512;
  u16* lB0 = Bs + w * 512;
  u16* lB1 = Bs + 2048 + w * 512;

  const u16* ap = As + (size_t)(mw + (lane & 15)) * 32 + (lane >> 4) * 8;
  const u16* bp = Bs + (size_t)(nw + (lane & 15)) * 32 + (lane >> 4) * 8;

  for (int k0 = 0; k0 < KP; k0 += 32) {
    __builtin_amdgcn_global_load_lds((gas_u32*)(ag0 + k0), (las_u32*)lA0, 16, 0, 0);
    __builtin_amdgcn_global_load_lds((gas_u32*)(ag1 + k0), (las_u32*)lA1, 16, 0, 0);
    if (BF32) {
      int kk = k0 + akq * 8;
#pragma unroll
      for (int t = 0; t < 2; ++t) {
        int rowg = t ? br1 : br0;
        const float* src = Bf + (size_t)rowg * ldb + kk;
        float4 v0 = (kk < Kreal)     ? *(const float4*)(src)     : make_float4(0.f, 0.f, 0.f, 0.f);
        float4 v1 = (kk + 4 < Kreal) ? *(const float4*)(src + 4) : make_float4(0.f, 0.f, 0.f, 0.f);
        u32x4 pk;
        pk.x = (unsigned)f2bf(v0.x) | ((unsigned)f2bf(v0.y) << 16);
        pk.y = (unsigned)f2bf(v0.z) | ((unsigned)f2bf(v0.w) << 16);
        pk.z = (unsigned)f2bf(v1.x) | ((unsigned)f2bf(v1.y) << 16);
        pk.w = (unsigned)f2bf(v1.z) | ((unsigned)f2bf(v1.w) << 16);
        *(u32x4*)(Bs + t * 2048 + tid * 8) = pk;
      }
    } else {
      __builtin_amdgcn_global_load_lds((gas_u32*)(bg0 + k0), (las_u32*)lB0, 16, 0, 0);
      __builtin_amdgcn_global_load_lds((gas_u32*)(bg1 + k0), (las_u32*)lB1, 16, 0, 0);
    }
    __syncthreads();
    s8v af[4], bf[4];
#pragma unroll
    for (int i = 0; i < 4; ++i) af[i] = *(const s8v*)(ap + i * 16 * 32);
#pragma unroll
    for (int j = 0; j < 4; ++j) bf[j] = *(const s8v*)(bp + j * 16 * 32);
#pragma unroll
    for (int i = 0; i < 4; ++i)
#pragma unroll
      for (int j = 0; j < 4; ++j)
        acc[i][j] = __builtin_amdgcn_mfma_f32_16x16x32_bf16(af[i], bf[j], acc[i][j], 0, 0, 0);
    __syncthreads();
  }

  const int quad = lane >> 4, col = lane & 15;
#pragma unroll
  for (int i = 0; i < 4; ++i) {
#pragma unroll
    for (int j = 0; j < 4; ++j) {
      int n = n0 + nw + 16 * j + col;
      if (n >= N) continue;
      float bv = bias[n];
#pragma unroll
      for (int r = 0; r < 4; ++r) {
        int m = m0 + mw + 16 * i + quad * 4 + r;
        float v = acc[i][j][r] + bv;
        if (RELU) v = fmaxf(v, 0.f);
        size_t off = (size_t)m * ldc + n;
        if (OUTBF) ((u16*)Cp)[off] = f2bf(v);
        else       ((float*)Cp)[off] = v;
      }
    }
  }
}

// ---------------------------------------------------------------- small VALU gemm (fp32 W from d_in)
__global__ __launch_bounds__(256) void sgemm_valu(
    const u16* __restrict__ X, int lda,
    const float* __restrict__ W, const float* __restrict__ bvec,
    float* __restrict__ Y, int ldc, int M, int N, int K) {
  int n0 = blockIdx.x * 64, m0 = blockIdx.y * 64;
  __shared__ float Xs[16][64];
  __shared__ float Ws[16][64];
  int tid = threadIdx.x;
  int tx = tid & 15, ty = tid >> 4;
  int lr = tid >> 2, lc = (tid & 3) << 2;
  float acc[4][4] = {};
  const u16* xbase = X + (size_t)(m0 + lr) * lda + lc;
  int wn = n0 + lr;
  bool wvalid = wn < N;
  const float* wbase = W + (size_t)(wvalid ? wn : 0) * K + lc;
  for (int k0 = 0; k0 < K; k0 += 16) {
#pragma unroll
    for (int j = 0; j < 4; ++j) Xs[lc + j][lr] = bf2f(xbase[k0 + j]);
#pragma unroll
    for (int j = 0; j < 4; ++j) Ws[lc + j][lr] = wvalid ? wbase[k0 + j] : 0.f;
    __syncthreads();
#pragma unroll
    for (int kk = 0; kk < 16; ++kk) {
      float xv[4], wv[4];
#pragma unroll
      for (int a = 0; a < 4; ++a) xv[a] = Xs[kk][ty * 4 + a];
#pragma unroll
      for (int b = 0; b < 4; ++b) wv[b] = Ws[kk][tx * 4 + b];
#pragma unroll
      for (int a = 0; a < 4; ++a)
#pragma unroll
        for (int b = 0; b < 4; ++b)
          acc[a][b] = fmaf(xv[a], wv[b], acc[a][b]);
    }
    __syncthreads();
  }
#pragma unroll
  for (int a = 0; a < 4; ++a) {
    int m = m0 + ty * 4 + a;
#pragma unroll
    for (int b = 0; b < 4; ++b) {
      int n = n0 + tx * 4 + b;
      if (n < N) Y[(size_t)m * ldc + n] = acc[a][b] + bvec[n];
    }
  }
}

// ---------------------------------------------------------------- attention
__device__ __forceinline__ float wave_sum(float v) {
#pragma unroll
  for (int o = 32; o > 0; o >>= 1) v += __shfl_xor(v, o);
  return v;
}

__global__ void score_kernel(const u16* __restrict__ qkv, float* __restrict__ att) {
  int bh = blockIdx.x;            // b*4 + h
  int h = bh & 3, b = bh >> 2;
  int lane = threadIdx.x;
  float s[4][4];
#pragma unroll
  for (int l = 0; l < 4; ++l) {
    const u16* qp = qkv + (size_t)(b * 4 + l) * 4800 + h * 400;
#pragma unroll
    for (int m = 0; m < 4; ++m) {
      const u16* kp = qkv + (size_t)(b * 4 + m) * 4800 + 1600 + h * 400;
      float p = 0.f;
      for (int d = lane; d < 400; d += 64) p += bf2f(qp[d]) * bf2f(kp[d]);
      s[l][m] = wave_sum(p) * 0.05f;   // 1/sqrt(400)
    }
  }
  if (lane < 16) {
    int l = lane >> 2, m = lane & 3;
    float mx = fmaxf(fmaxf(s[l][0], s[l][1]), fmaxf(s[l][2], s[l][3]));
    float e0 = expf(s[l][0] - mx), e1 = expf(s[l][1] - mx);
    float e2 = expf(s[l][2] - mx), e3 = expf(s[l][3] - mx);
    float inv = 1.f / (e0 + e1 + e2 + e3);
    float ev = (m == 0) ? e0 : (m == 1) ? e1 : (m == 2) ? e2 : e3;
    att[(size_t)bh * 16 + l * 4 + m] = ev * inv;
  }
}

// o[b,l,h,d] = sum_m att[b,h,l,m] * v[b,m,h,d]; v at qkv col offset 3200
__global__ void attn_apply_kernel(const float* __restrict__ att, const u16* __restrict__ qkv,
                                  u16* __restrict__ o) {
  int idx = blockIdx.x * 256 + threadIdx.x;
  if (idx >= 2048 * 1600) return;
  int col = idx % 1600;       // h*400 + d
  int row = idx / 1600;       // b*4 + l
  int b = row >> 2, l = row & 3, h = col / 400;
  const float* ap = att + ((size_t)b * 4 + h) * 16 + l * 4;
  float acc = 0.f;
#pragma unroll
  for (int m = 0; m < 4; ++m)
    acc += ap[m] * bf2f(qkv[(size_t)(b * 4 + m) * 4800 + 3200 + col]);
  o[idx] = f2bf(acc);
}

// ---------------------------------------------------------------- rowwise LN(A_bf16 + Bv_f32), len 400
__global__ __launch_bounds__(128) void ln_kernel(const u16* __restrict__ A, int lda,
                                                 const float* __restrict__ Bv, int ldb,
                                                 const float* __restrict__ g, const float* __restrict__ beta,
                                                 u16* __restrict__ out, int ldo) {
  int row = blockIdx.x;
  int tid = threadIdx.x;
  const u16* a = A + (size_t)row * lda;
  const float* bb = Bv + (size_t)row * ldb;
  float vals[4] = {};
  float s = 0.f, q = 0.f;
#pragma unroll
  for (int j = 0; j < 4; ++j) {
    int d = tid + j * 128;
    if (d < 400) { float x = bf2f(a[d]) + bb[d]; vals[j] = x; s += x; q += x * x; }
  }
  __shared__ float rs[128], rq[128];
  rs[tid] = s; rq[tid] = q;
  __syncthreads();
  for (int off = 64; off > 0; off >>= 1) {
    if (tid < off) { rs[tid] += rs[tid + off]; rq[tid] += rq[tid + off]; }
    __syncthreads();
  }
  float mean = rs[0] * (1.f / 400.f);
  float var = rq[0] * (1.f / 400.f) - mean * mean;
  float rstd = rsqrtf(var + 1e-5f);
  u16* op = out + (size_t)row * ldo;
#pragma unroll
  for (int j = 0; j < 4; ++j) {
    int d = tid + j * 128;
    if (d < 400) op[d] = f2bf((vals[j] - mean) * rstd * g[d] + beta[d]);
  }
}

// ---------------------------------------------------------------- global sum/sumsq partials (atomic)
template<typename T>
__global__ __launch_bounds__(256) void stat_partial(const T* __restrict__ base, long long slice_stride,
                                                    int row_stride, int len, long long total, int nb,
                                                    float* __restrict__ sums) {
  int slice = blockIdx.x / nb, chunk = blockIdx.x % nb;
  const T* p = base + (size_t)slice * slice_stride;
  int tid = threadIdx.x;
  float s = 0.f, q = 0.f;
  long long step = (long long)nb * 256;
  for (long long t = (long long)chunk * 256 + tid; t < total; t += step) {
    int row = (int)(t / len), colx = (int)(t % len);
    float x;
    if (sizeof(T) == 2) x = bf2f(((const u16*)p)[(size_t)row * row_stride + colx]);
    else                x = ((const float*)p)[(size_t)row * row_stride + colx];
    s += x; q += x * x;
  }
  __shared__ float rs[256], rq[256];
  rs[tid] = s; rq[tid] = q;
  __syncthreads();
  for (int off = 128; off > 0; off >>= 1) {
    if (tid < off) { rs[tid] += rs[tid + off]; rq[tid] += rq[tid + off]; }
    __syncthreads();
  }
  if (tid == 0) {
    atomicAdd(&sums[2 * slice], rs[0]);
    atomicAdd(&sums[2 * slice + 1], rq[0]);
  }
}

__device__ __forceinline__ void mean_rstd(const float* sums, float count, float& m, float& rstd) {
  m = sums[0] / count;
  float var = sums[1] / count - m * m;
  rstd = rsqrtf(var + 1e-5f);
}

// ---------------------------------------------------------------- y3[i][b][p*400+d] = f[b,p]*xn(x2[b,i+1,d])
__global__ void build_y3_kernel(const u16* __restrict__ x2, const float* __restrict__ f,
                                const float* __restrict__ scal, const float* __restrict__ pg,
                                const float* __restrict__ pb, u16* __restrict__ y3) {
  int idx = blockIdx.x * 256 + threadIdx.x;
  if (idx >= 3 * 512 * 6400) return;
  int d = idx % 400;
  int p = (idx / 400) % 16;
  int b = (idx / 6400) % 512;
  int i = idx / (512 * 6400);
  float m, rstd;
  mean_rstd(scal + 2 * i, 204800.f, m, rstd);
  float e = bf2f(x2[(size_t)(b * 4 + i + 1) * 400 + d]);
  float xn = (e - m) * rstd * pg[0] + pb[0];
  y3[idx] = f2bf(f[b * 16 + p] * xn);
}

// ---------------------------------------------------------------- conv (bkj,bij->bki) + pairwise maxpool
// efI layout: [arity i][b][d] (rows 1536 x 400).  flat[b][p] = efI[(p/400)*512 + b][p%400]
__global__ void convpool_kernel(const float* __restrict__ kern, const float* __restrict__ efI,
                                const float* __restrict__ scal, const float* __restrict__ bg_,
                                const float* __restrict__ bb_, u16* __restrict__ pooled) {
  int idx = blockIdx.x * 256 + threadIdx.x;
  if (idx >= 512 * 32 * 200) return;
  int i2 = idx % 200;
  int k = (idx / 200) % 32;
  int b = idx / 6400;
  float m, rstd;
  mean_rstd(scal, 614400.f, m, rstd);
  float bg = bg_[0], bb = bb_[0];
  const float* kp = kern + (size_t)b * 96 + k * 3;
  float c0 = 0.f, c1 = 0.f;
#pragma unroll
  for (int j = 0; j < 3; ++j) {
    int p0 = 6 * i2 + j;
    int p1 = 6 * i2 + 3 + j;
    float e0 = efI[(size_t)(p0 / 400) * 204800 + (size_t)b * 400 + (p0 % 400)];
    float e1 = efI[(size_t)(p1 / 400) * 204800 + (size_t)b * 400 + (p1 % 400)];
    c0 += kp[j] * ((e0 - m) * rstd * bg + bb);
    c1 += kp[j] * ((e1 - m) * rstd * bg + bb);
  }
  pooled[(size_t)b * 6400 + k * 200 + i2] = f2bf(fmaxf(c0, c1));
}

// ---------------------------------------------------------------- launch
extern "C" void kernel_launch(void* const* d_in, const int* in_sizes, int n_in,
                              void* d_out, int out_size, void* d_ws, size_t ws_size,
                              hipStream_t stream) {
  const float* ent_emb    = (const float*)d_in[0];
  const float* rel_emb    = (const float*)d_in[1];
  const float* pos_emb    = (const float*)d_in[2];
  const float* relposw_w  = (const float*)d_in[3];
  const float* relposw_b  = (const float*)d_in[4];
  const float* relposinv_w= (const float*)d_in[5];
  const float* relposinv_b= (const float*)d_in[6];
  const float* relw4_w    = (const float*)d_in[7];
  const float* relw4_b    = (const float*)d_in[8];
  const float* q_w        = (const float*)d_in[9];
  const float* q_b        = (const float*)d_in[10];
  const float* k_w        = (const float*)d_in[11];
  const float* k_b        = (const float*)d_in[12];
  const float* v_w        = (const float*)d_in[13];
  const float* v_b        = (const float*)d_in[14];
  const float* fca_w      = (const float*)d_in[15];
  const float* fca_b      = (const float*)d_in[16];
  const float* ln1_g      = (const float*)d_in[17];
  const float* ln1_b      = (const float*)d_in[18];
  const float* ln2_g      = (const float*)d_in[19];
  const float* ln2_b      = (const float*)d_in[20];
  const float* w1_w       = (const float*)d_in[21];
  const float* w1_b       = (const float*)d_in[22];
  const float* w2_w       = (const float*)d_in[23];
  const float* w2_b       = (const float*)d_in[24];
  const float* fc_w       = (const float*)d_in[25];
  const float* fc_b       = (const float*)d_in[26];
  const float* posbn_g    = (const float*)d_in[27];
  const float* posbn_b    = (const float*)d_in[28];
  const float* bn_g       = (const float*)d_in[29];
  const float* bn_b       = (const float*)d_in[30];
  const float* bias       = (const float*)d_in[31];
  const int*  rel_idx     = (const int*)d_in[32];
  const int*  ent_idx     = (const int*)d_in[33];

  char* base = (char*)d_ws;
  // ---- persistent arena (57.9 MB base + optional 166.4 MB bf16 ent_emb) ----
  u16*   wqkv  = (u16*)(base + 0);          // 4800x416 bf16
  u16*   wfca  = (u16*)(base + 3993600);    // 400x1600
  u16*   ww1   = (u16*)(base + 5273600);    // 800x416
  u16*   ww2   = (u16*)(base + 5939200);    // 400x800
  u16*   wrpi  = (u16*)(base + 6579200);    // 400x6400
  u16*   wfc   = (u16*)(base + 11699200);   // 400x6400
  float* qkvb  = (float*)(base + 16819200); // 4800 f32 (concat q_b|k_b|v_b)
  u16*   x0    = (u16*)(base + 16838400);   // 2048x416
  u16*   x1    = (u16*)(base + 18542336);   // 2048x416
  u16*   hbuf  = (u16*)(base + 20246272);   // 512x416
  float* att   = (float*)(base + 20672256); // 512x4x16
  float* tmp32 = (float*)(base + 20803328); // 2048x400 f32 (fca out, then w2 out)
  u16*   x2    = (u16*)(base + 24080128);   // 2048x400
  float* fbuf  = (float*)(base + 25718528); // 512x16
  float* kern  = (float*)(base + 25751296); // 512x96
  float* efI   = (float*)(base + 25947904); // 1536x400 f32
  float* scal  = (float*)(base + 28405504); // 16 f32 (sum/sumsq pairs)
  u16*   qkvbuf= (u16*)(base + 28405760);   // 2048x4800 (alias: y3 1536x6400)
  u16*   y3    = qkvbuf;
  u16*   obuf  = (u16*)(base + 48066560);   // 2048x1600 (alias: pooled 512x6400)
  u16*   pooled= obuf;
  u16*   ffn1  = (u16*)(base + 54620160);   // 2048x800
  u16*   entbf = (u16*)(base + 57896960);   // 200000x416 bf16 (optional, 166.4 MB)
  const bool big_ws = ws_size >= 224296960ull;

  dim3 blk(256);

  // zero padded activation buffers (x0|x1|hbuf contiguous) + stat accumulators
  hipMemsetAsync(base + 16838400, 0, 3833856, stream);
  hipMemsetAsync(scal, 0, 64, stream);

  // concat qkv bias
  hipMemcpyAsync(qkvb,        q_b, 1600 * 4, hipMemcpyDeviceToDevice, stream);
  hipMemcpyAsync(qkvb + 1600, k_b, 1600 * 4, hipMemcpyDeviceToDevice, stream);
  hipMemcpyAsync(qkvb + 3200, v_b, 1600 * 4, hipMemcpyDeviceToDevice, stream);

  // weight conversions (fp32 -> bf16, K-padded)
  convert_w_kernel<<<(1600 * 416 + 255) / 256, blk, 0, stream>>>(q_w, wqkv,              1600, 400, 416);
  convert_w_kernel<<<(1600 * 416 + 255) / 256, blk, 0, stream>>>(k_w, wqkv + 1600 * 416, 1600, 400, 416);
  convert_w_kernel<<<(1600 * 416 + 255) / 256, blk, 0, stream>>>(v_w, wqkv + 3200 * 416, 1600, 400, 416);
  convert_w_kernel<<<(400 * 1600 + 255) / 256, blk, 0, stream>>>(fca_w, wfca, 400, 1600, 1600);
  convert_w_kernel<<<(800 * 416 + 255) / 256,  blk, 0, stream>>>(w1_w, ww1, 800, 400, 416);
  convert_w_kernel<<<(400 * 800 + 255) / 256,  blk, 0, stream>>>(w2_w, ww2, 400, 800, 800);
  convert_w_kernel<<<(400 * 6400 + 255) / 256, blk, 0, stream>>>(relposinv_w, wrpi, 400, 6400, 6400);
  convert_w_kernel<<<(400 * 6400 + 255) / 256, blk, 0, stream>>>(fc_w, wfc, 400, 6400, 6400);

  // x0 = gather + pos
  build_x0_kernel<<<3200, blk, 0, stream>>>(ent_emb, rel_emb, pos_emb, rel_idx, ent_idx, x0);

  // fused qkv: (2048,416) @ (4800,416)^T -> qkvbuf bf16
  mfma_gemm<false, false, true, false><<<dim3(16, 38), blk, 0, stream>>>(
      x0, 416, wqkv, 416, qkvb, qkvbuf, 4800, 4800, 416, 416);

  score_kernel<<<2048, 64, 0, stream>>>(qkvbuf, att);
  attn_apply_kernel<<<12800, blk, 0, stream>>>(att, qkvbuf, obuf);

  // fca: o(2048,1600) @ (400,1600)^T -> tmp32
  mfma_gemm<false, false, false, false><<<dim3(16, 4), blk, 0, stream>>>(
      obuf, 1600, wfca, 1600, fca_b, tmp32, 400, 400, 1600, 1600);
  ln_kernel<<<2048, 128, 0, stream>>>(x0, 416, tmp32, 400, ln1_g, ln1_b, x1, 416);

  // FFN
  mfma_gemm<false, true, true, false><<<dim3(16, 7), blk, 0, stream>>>(
      x1, 416, ww1, 416, w1_b, ffn1, 800, 800, 416, 416);
  mfma_gemm<false, false, false, false><<<dim3(16, 4), blk, 0, stream>>>(
      ffn1, 800, ww2, 800, w2_b, tmp32, 400, 400, 800, 800);
  ln_kernel<<<2048, 128, 0, stream>>>(x1, 416, tmp32, 400, ln2_g, ln2_b, x2, 400);

  // f = r @ relposw^T ; kern = r @ relw4^T   (r = x2[:,0,:], row stride 1600)
  sgemm_valu<<<dim3(1, 8), blk, 0, stream>>>(x2, 1600, relposw_w, relposw_b, fbuf, 16, 512, 16, 400);
  sgemm_valu<<<dim3(2, 8), blk, 0, stream>>>(x2, 1600, relw4_w, relw4_b, kern, 96, 512, 96, 400);

  // global stats of x2[:, i+1, :] (3 slices) -> scal[0..5] (sum/sumsq)
  stat_partial<u16><<<3 * 16, blk, 0, stream>>>(x2 + 400, 400, 1600, 400, 204800, 16, scal);

  // y3 = f ⊗ xn (3 slices batched), then ef = y3 @ relposinv^T (M=1536)
  build_y3_kernel<<<38400, blk, 0, stream>>>(x2, fbuf, scal, posbn_g, posbn_b, y3);
  mfma_gemm<false, false, false, false><<<dim3(12, 4), blk, 0, stream>>>(
      y3, 6400, wrpi, 6400, relposinv_b, efI, 400, 400, 6400, 6400);

  // global stats of ef -> scal[6..7]
  stat_partial<float><<<32, blk, 0, stream>>>(efI, 0, 400, 400, 614400, 32, scal + 6);

  // conv + maxpool -> pooled bf16
  convpool_kernel<<<12800, blk, 0, stream>>>(kern, efI, scal + 6, bn_g, bn_b, pooled);

  // h = relu(pooled @ fc^T) -> hbuf (bf16, ld 416, pad pre-zeroed)
  mfma_gemm<false, true, true, false><<<dim3(4, 4), blk, 0, stream>>>(
      pooled, 6400, wfc, 6400, fc_b, hbuf, 416, 400, 6400, 6400);

  // out = h @ ent_emb^T + bias  (M=512, N=200000)
  if (big_ws) {
    // pre-convert ent_emb to bf16 (K-padded to 416), then all-bf16 global_load_lds path.
    // Placed here (late) so the 166 MB bf16 copy is L3-resident when the GEMM reads it.
    convert_ent_kernel<<<40625, blk, 0, stream>>>(ent_emb, entbf);
    mfma_gemm<false, false, false, true><<<dim3(4, 1563), blk, 0, stream>>>(
        hbuf, 416, entbf, 416, bias, d_out, 200000, 200000, 416, 416);
  } else {
    // fallback: fp32 B staged in-kernel (swizzled for L2 panel reuse)
    mfma_gemm<true, false, false, true><<<dim3(4, 1563), blk, 0, stream>>>(
        hbuf, 416, ent_emb, 400, bias, d_out, 200000, 200000, 416, 400);
  }
}